// Round 3
// baseline (94207.056 us; speedup 1.0000x reference)
//
#include <hip/hip_runtime.h>
#include <math.h>

#define BATCH 131072
#define NSTEPS 256

using f32x2 = __attribute__((ext_vector_type(2))) float;

__device__ __forceinline__ float fast_exp(float x) {
    return __builtin_amdgcn_exp2f(x * 1.44269504088896340736f);
}
__device__ __forceinline__ float fast_rcp(float x) {
    return __builtin_amdgcn_rcpf(x);
}
__device__ __forceinline__ float sigmoidf_fast(float x) {
    return fast_rcp(1.0f + fast_exp(-x));
}

__global__ __launch_bounds__(256, 4) void deep_hedging_kernel(
    const float* __restrict__ noise,   // (NSTEPS, BATCH)
    const float* __restrict__ ts,      // (NSTEPS+1)
    const float* __restrict__ w,       // scalar
    const float* __restrict__ W1,      // (32,2)
    const float* __restrict__ b1,      // (32)
    const float* __restrict__ W2,      // (32,32)
    const float* __restrict__ b2,      // (32)
    const float* __restrict__ W3,      // (1,32)
    const float* __restrict__ b3,      // (1)
    float* __restrict__ out)           // (BATCH)
{
    __shared__ float sW1[64];
    __shared__ float sb1[32];
    __shared__ float sW2[1024];
    __shared__ float sb2[32];
    __shared__ float sW3[32];
    __shared__ float sb3w[2];
    __shared__ float sts[NSTEPS + 1];

    const int tid = threadIdx.x;
    for (int i = tid; i < 1024; i += 256) sW2[i] = W2[i];
    if (tid < 64) sW1[tid] = W1[tid];
    if (tid < 32) { sb1[tid] = b1[tid]; sb2[tid] = b2[tid]; sW3[tid] = W3[tid]; }
    if (tid == 0) { sb3w[0] = b3[0]; sb3w[1] = w[0]; }
    for (int i = tid; i < NSTEPS + 1; i += 256) sts[i] = ts[i];
    __syncthreads();

    const int gid = blockIdx.x * 256 + tid;
    const float* np_ = noise + gid;

    float s   = 1.0f;   // y[:,0]
    float pnl = 0.0f;   // y[:,1]
    const float b3v = sb3w[0];

    #pragma unroll 1
    for (int st = 0; st < NSTEPS; ++st) {
        const float t  = sts[st];
        const float dt = sts[st + 1] - t;
        const float dW = np_[(size_t)st * BATCH] * __builtin_sqrtf(dt);

        // ---- MLP forward + JVP tangent. input x=(t,s), tangent (0, sd), sd = SIGMA*s
        const float sd = s;  // SIGMA = 1
        f32x2 at1[32];       // {silu(z1), silu'(z1)*zd} per hidden unit
        #pragma unroll
        for (int j = 0; j < 32; ++j) {
            const float w0 = sW1[2 * j];
            const float w1 = sW1[2 * j + 1];
            const float z  = fmaf(w0, t, fmaf(w1, s, sb1[j]));
            const float zd = w1 * sd;
            const float sg = sigmoidf_fast(z);
            const float da = sg * (1.0f + z * (1.0f - sg));  // silu'(z)
            at1[j].x = z * sg;                                // silu(z)
            at1[j].y = da * zd;
        }

        f32x2 acc2 = {b3v, 0.0f};
        #pragma unroll
        for (int j = 0; j < 32; ++j) {
            f32x2 zz = {sb2[j], 0.0f};
            #pragma unroll
            for (int i = 0; i < 32; ++i) {
                const float wv = sW2[j * 32 + i];
                zz += f32x2{wv, wv} * at1[i];   // v_pk_fma_f32 candidate
            }
            const float z  = zz.x;
            const float zd = zz.y;
            const float sg = sigmoidf_fast(z);
            const float da = sg * (1.0f + z * (1.0f - sg));
            const float w3 = sW3[j];
            acc2 += f32x2{w3, w3} * f32x2{z * sg, da * zd};
        }
        const float h  = sigmoidf_fast(acc2.x);
        const float hd = h * (1.0f - h) * acc2.y;   // tangent of h along JVP direction

        // Milstein update (MU = SIGMA = 1):
        // f=(s, s*h); g=(s, s*h); dg=(sd, sd*h + s*hd)
        const float mil = 0.5f * (dW * dW - dt);
        const float g1  = s * h;
        const float dg1 = fmaf(sd, h, s * hd);

        const float snew = s + s * dt + s * dW + sd * mil;
        pnl = pnl + g1 * dt + g1 * dW + dg1 * mil;
        s = snew;
    }

    const float z = fmaxf(0.0f, s - 3.0f);
    const float d = z - pnl - sb3w[1];
    out[gid] = d * d;
}

extern "C" void kernel_launch(void* const* d_in, const int* in_sizes, int n_in,
                              void* d_out, int out_size, void* d_ws, size_t ws_size,
                              hipStream_t stream) {
    const float* noise = (const float*)d_in[0];
    const float* ts    = (const float*)d_in[1];
    const float* w     = (const float*)d_in[2];
    const float* W1    = (const float*)d_in[3];
    const float* b1    = (const float*)d_in[4];
    const float* W2    = (const float*)d_in[5];
    const float* b2    = (const float*)d_in[6];
    const float* W3    = (const float*)d_in[7];
    const float* b3    = (const float*)d_in[8];
    float* out = (float*)d_out;

    dim3 grid(BATCH / 256), block(256);
    deep_hedging_kernel<<<grid, block, 0, stream>>>(noise, ts, w, W1, b1, W2, b2,
                                                    W3, b3, out);
}

// Round 4
// 2504.891 us; speedup vs baseline: 37.6092x; 37.6092x over previous
//
#include <hip/hip_runtime.h>
#include <math.h>

#define BATCH 131072
#define NSTEPS 256

using f32x2 = __attribute__((ext_vector_type(2))) float;

__device__ __forceinline__ float fast_exp(float x) {
    return __builtin_amdgcn_exp2f(x * 1.44269504088896340736f);
}
__device__ __forceinline__ float fast_rcp(float x) {
    return __builtin_amdgcn_rcpf(x);
}
__device__ __forceinline__ float sigmoidf_fast(float x) {
    return fast_rcp(1.0f + fast_exp(-x));
}

#define REP32(M) M(0) M(1) M(2) M(3) M(4) M(5) M(6) M(7) \
                 M(8) M(9) M(10) M(11) M(12) M(13) M(14) M(15) \
                 M(16) M(17) M(18) M(19) M(20) M(21) M(22) M(23) \
                 M(24) M(25) M(26) M(27) M(28) M(29) M(30) M(31)

__global__ __launch_bounds__(256, 3) void deep_hedging_kernel(
    const float* __restrict__ noise,   // (NSTEPS, BATCH)
    const float* __restrict__ ts,      // (NSTEPS+1)
    const float* __restrict__ w,       // scalar
    const float* __restrict__ W1,      // (32,2)
    const float* __restrict__ b1,      // (32)
    const float* __restrict__ W2,      // (32,32)
    const float* __restrict__ b2,      // (32)
    const float* __restrict__ W3,      // (1,32)
    const float* __restrict__ b3,      // (1)
    float* __restrict__ out)           // (BATCH)
{
    __shared__ __align__(16) float sW1[64];
    __shared__ float sb1[32];
    __shared__ __align__(16) float sW2[1024];
    __shared__ float sb2[32];
    __shared__ float sW3[32];
    __shared__ float sb3w[2];
    __shared__ float sts[NSTEPS + 1];

    const int tid = threadIdx.x;
    for (int i = tid; i < 1024; i += 256) sW2[i] = W2[i];
    if (tid < 64) sW1[tid] = W1[tid];
    if (tid < 32) { sb1[tid] = b1[tid]; sb2[tid] = b2[tid]; sW3[tid] = W3[tid]; }
    if (tid == 0) { sb3w[0] = b3[0]; sb3w[1] = w[0]; }
    for (int i = tid; i < NSTEPS + 1; i += 256) sts[i] = ts[i];
    __syncthreads();

    const int gid = blockIdx.x * 256 + tid;
    const float* np_ = noise + gid;

    float s   = 1.0f;   // y[:,0]
    float pnl = 0.0f;   // y[:,1]
    const float b3v = sb3w[0];
    const float wv_ = sb3w[1];

    #pragma unroll 1
    for (int st = 0; st < NSTEPS; ++st) {
        // Opaque zero: makes every LDS weight address loop-variant to the
        // compiler so LICM cannot hoist weight loads across step iterations
        // (that hoisting caused the R1 VGPR blowup / spill storm).
        int zr = 0;
        asm volatile("" : "+v"(zr));
        const float2* W1r = (const float2*)sW1 + zr;
        const float*  B1  = sb1 + zr;
        const float4* W2r = (const float4*)sW2 + zr;
        const float*  B2  = sb2 + zr;
        const float*  W3r = sW3 + zr;

        const float t  = sts[st];
        const float dt = sts[st + 1] - t;
        const float dW = np_[(size_t)st * BATCH] * __builtin_sqrtf(dt);

        // ---- Layer 1 + tangent. x=(t,s), tangent dir (0, sd), sd = SIGMA*s
        const float sd = s;  // SIGMA = 1
        #define L1(j) f32x2 at##j; { \
            const float2 wv = W1r[j]; \
            const float z  = fmaf(wv.x, t, fmaf(wv.y, s, B1[j])); \
            const float zd = wv.y * sd; \
            const float sg = sigmoidf_fast(z); \
            const float da = sg * (1.0f + z * (1.0f - sg)); \
            at##j = (f32x2){z * sg, da * zd}; }
        REP32(L1)
        #undef L1

        // ---- Layer 2 (32x32) + layer 3 dot, value+tangent packed in f32x2
        f32x2 acc2 = {b3v, 0.0f};
        #define ROW(j) { \
            const float4 q0 = W2r[(j) * 8 + 0]; \
            const float4 q1 = W2r[(j) * 8 + 1]; \
            const float4 q2 = W2r[(j) * 8 + 2]; \
            const float4 q3 = W2r[(j) * 8 + 3]; \
            const float4 q4 = W2r[(j) * 8 + 4]; \
            const float4 q5 = W2r[(j) * 8 + 5]; \
            const float4 q6 = W2r[(j) * 8 + 6]; \
            const float4 q7 = W2r[(j) * 8 + 7]; \
            f32x2 zza = {B2[j], 0.0f}; \
            f32x2 zzb = {0.0f, 0.0f}; \
            zza += (f32x2){q0.x, q0.x} * at0;  zzb += (f32x2){q0.y, q0.y} * at1; \
            zza += (f32x2){q0.z, q0.z} * at2;  zzb += (f32x2){q0.w, q0.w} * at3; \
            zza += (f32x2){q1.x, q1.x} * at4;  zzb += (f32x2){q1.y, q1.y} * at5; \
            zza += (f32x2){q1.z, q1.z} * at6;  zzb += (f32x2){q1.w, q1.w} * at7; \
            zza += (f32x2){q2.x, q2.x} * at8;  zzb += (f32x2){q2.y, q2.y} * at9; \
            zza += (f32x2){q2.z, q2.z} * at10; zzb += (f32x2){q2.w, q2.w} * at11; \
            zza += (f32x2){q3.x, q3.x} * at12; zzb += (f32x2){q3.y, q3.y} * at13; \
            zza += (f32x2){q3.z, q3.z} * at14; zzb += (f32x2){q3.w, q3.w} * at15; \
            zza += (f32x2){q4.x, q4.x} * at16; zzb += (f32x2){q4.y, q4.y} * at17; \
            zza += (f32x2){q4.z, q4.z} * at18; zzb += (f32x2){q4.w, q4.w} * at19; \
            zza += (f32x2){q5.x, q5.x} * at20; zzb += (f32x2){q5.y, q5.y} * at21; \
            zza += (f32x2){q5.z, q5.z} * at22; zzb += (f32x2){q5.w, q5.w} * at23; \
            zza += (f32x2){q6.x, q6.x} * at24; zzb += (f32x2){q6.y, q6.y} * at25; \
            zza += (f32x2){q6.z, q6.z} * at26; zzb += (f32x2){q6.w, q6.w} * at27; \
            zza += (f32x2){q7.x, q7.x} * at28; zzb += (f32x2){q7.y, q7.y} * at29; \
            zza += (f32x2){q7.z, q7.z} * at30; zzb += (f32x2){q7.w, q7.w} * at31; \
            const f32x2 zzt = zza + zzb; \
            const float zv  = zzt.x; \
            const float sg  = sigmoidf_fast(zv); \
            const float da  = sg * (1.0f + zv * (1.0f - sg)); \
            const float w3  = W3r[j]; \
            acc2 += (f32x2){w3, w3} * (f32x2){zv * sg, da * zzt.y}; \
        }
        REP32(ROW)
        #undef ROW

        const float h  = sigmoidf_fast(acc2.x);
        const float hd = h * (1.0f - h) * acc2.y;   // tangent of h

        // Milstein update (MU = SIGMA = 1):
        // f=(s, s*h); g=(s, s*h); dg=(sd, sd*h + s*hd)
        const float mil = 0.5f * (dW * dW - dt);
        const float g1  = s * h;
        const float dg1 = fmaf(sd, h, s * hd);

        const float snew = s + s * dt + s * dW + sd * mil;
        pnl = pnl + g1 * dt + g1 * dW + dg1 * mil;
        s = snew;
    }

    const float z = fmaxf(0.0f, s - 3.0f);
    const float d = z - pnl - wv_;
    out[gid] = d * d;
}

extern "C" void kernel_launch(void* const* d_in, const int* in_sizes, int n_in,
                              void* d_out, int out_size, void* d_ws, size_t ws_size,
                              hipStream_t stream) {
    const float* noise = (const float*)d_in[0];
    const float* ts    = (const float*)d_in[1];
    const float* w     = (const float*)d_in[2];
    const float* W1    = (const float*)d_in[3];
    const float* b1    = (const float*)d_in[4];
    const float* W2    = (const float*)d_in[5];
    const float* b2    = (const float*)d_in[6];
    const float* W3    = (const float*)d_in[7];
    const float* b3    = (const float*)d_in[8];
    float* out = (float*)d_out;

    dim3 grid(BATCH / 256), block(256);
    deep_hedging_kernel<<<grid, block, 0, stream>>>(noise, ts, w, W1, b1, W2, b2,
                                                    W3, b3, out);
}

// Round 5
// 135.902 us; speedup vs baseline: 693.1992x; 18.4316x over previous
//
#include <hip/hip_runtime.h>
#include <math.h>

#define BATCH 131072
#define NSTEPS 256
#define LOGLO -16.0f
#define LOGSPAN 26.0f

using f32x2 = __attribute__((ext_vector_type(2))) float;

__device__ __forceinline__ float fast_exp(float x) {
    return __builtin_amdgcn_exp2f(x * 1.44269504088896340736f);
}
__device__ __forceinline__ float fast_rcp(float x) {
    return __builtin_amdgcn_rcpf(x);
}
__device__ __forceinline__ float sigmoidf_fast(float x) {
    return fast_rcp(1.0f + fast_exp(-x));
}

#define REP32(M) M(0) M(1) M(2) M(3) M(4) M(5) M(6) M(7) \
                 M(8) M(9) M(10) M(11) M(12) M(13) M(14) M(15) \
                 M(16) M(17) M(18) M(19) M(20) M(21) M(22) M(23) \
                 M(24) M(25) M(26) M(27) M(28) M(29) M(30) M(31)

// Shared MLP+tangent body. Inputs: t, s, tangent scale sd (d/ds direction).
// Produces: h (sigmoid output) and hacc (pre-sigmoid tangent accumulator),
// i.e. hd = h*(1-h)*hacc is the directional derivative.
#define MLP_BODY(W1r, B1, W2r, B2, W3r, b3v, t, s, sd, H, HACC) \
    { \
        _Pragma("clang diagnostic push") \
        const float __t = (t), __s = (s), __sd = (sd); \
        f32x2 acc2 = {(b3v), 0.0f}; \
        { \
        _Pragma("clang diagnostic pop") \
        } \
        /* layer 1 */ \
        REP32(MLP_L1) \
        /* layer 2 + 3 */ \
        REP32(MLP_ROW) \
        H = sigmoidf_fast(acc2.x); \
        HACC = acc2.y; \
    }

#define MLP_L1(j) f32x2 at##j; { \
    const float2 wv = W1r[j]; \
    const float z  = fmaf(wv.x, __t, fmaf(wv.y, __s, B1[j])); \
    const float zd = wv.y * __sd; \
    const float sg = sigmoidf_fast(z); \
    const float da = sg * (1.0f + z * (1.0f - sg)); \
    at##j = (f32x2){z * sg, da * zd}; }

#define MLP_ROW(j) { \
    const float4 q0 = W2r[(j) * 8 + 0]; \
    const float4 q1 = W2r[(j) * 8 + 1]; \
    const float4 q2 = W2r[(j) * 8 + 2]; \
    const float4 q3 = W2r[(j) * 8 + 3]; \
    const float4 q4 = W2r[(j) * 8 + 4]; \
    const float4 q5 = W2r[(j) * 8 + 5]; \
    const float4 q6 = W2r[(j) * 8 + 6]; \
    const float4 q7 = W2r[(j) * 8 + 7]; \
    f32x2 zza = {B2[j], 0.0f}; \
    f32x2 zzb = {0.0f, 0.0f}; \
    zza += (f32x2){q0.x, q0.x} * at0;  zzb += (f32x2){q0.y, q0.y} * at1; \
    zza += (f32x2){q0.z, q0.z} * at2;  zzb += (f32x2){q0.w, q0.w} * at3; \
    zza += (f32x2){q1.x, q1.x} * at4;  zzb += (f32x2){q1.y, q1.y} * at5; \
    zza += (f32x2){q1.z, q1.z} * at6;  zzb += (f32x2){q1.w, q1.w} * at7; \
    zza += (f32x2){q2.x, q2.x} * at8;  zzb += (f32x2){q2.y, q2.y} * at9; \
    zza += (f32x2){q2.z, q2.z} * at10; zzb += (f32x2){q2.w, q2.w} * at11; \
    zza += (f32x2){q3.x, q3.x} * at12; zzb += (f32x2){q3.y, q3.y} * at13; \
    zza += (f32x2){q3.z, q3.z} * at14; zzb += (f32x2){q3.w, q3.w} * at15; \
    zza += (f32x2){q4.x, q4.x} * at16; zzb += (f32x2){q4.y, q4.y} * at17; \
    zza += (f32x2){q4.z, q4.z} * at18; zzb += (f32x2){q4.w, q4.w} * at19; \
    zza += (f32x2){q5.x, q5.x} * at20; zzb += (f32x2){q5.y, q5.y} * at21; \
    zza += (f32x2){q5.z, q5.z} * at22; zzb += (f32x2){q5.w, q5.w} * at23; \
    zza += (f32x2){q6.x, q6.x} * at24; zzb += (f32x2){q6.y, q6.y} * at25; \
    zza += (f32x2){q6.z, q6.z} * at26; zzb += (f32x2){q6.w, q6.w} * at27; \
    zza += (f32x2){q7.x, q7.x} * at28; zzb += (f32x2){q7.y, q7.y} * at29; \
    zza += (f32x2){q7.z, q7.z} * at30; zzb += (f32x2){q7.w, q7.w} * at31; \
    const f32x2 zzt = zza + zzb; \
    const float zv  = zzt.x; \
    const float sg  = sigmoidf_fast(zv); \
    const float da  = sg * (1.0f + zv * (1.0f - sg)); \
    const float w3  = W3r[j]; \
    acc2 += (f32x2){w3, w3} * (f32x2){zv * sg, da * zzt.y}; \
}

// ---------------------------------------------------------------------------
// Kernel 1: build per-step lookup table T[st][k] = {h, dh/ds} at
// s = 2^(lo + k*dx), t = ts[st].
// ---------------------------------------------------------------------------
__global__ __launch_bounds__(256) void table_kernel(
    const float* __restrict__ ts,
    const float* __restrict__ W1, const float* __restrict__ b1,
    const float* __restrict__ W2, const float* __restrict__ b2,
    const float* __restrict__ W3, const float* __restrict__ b3,
    float2* __restrict__ T, int lgnpts, float lo, float dx)
{
    __shared__ __align__(16) float sW1[64];
    __shared__ float sb1[32];
    __shared__ __align__(16) float sW2[1024];
    __shared__ float sb2[32];
    __shared__ float sW3[32];
    __shared__ float sb3[1];

    const int tid = threadIdx.x;
    for (int i = tid; i < 1024; i += 256) sW2[i] = W2[i];
    if (tid < 64) sW1[tid] = W1[tid];
    if (tid < 32) { sb1[tid] = b1[tid]; sb2[tid] = b2[tid]; sW3[tid] = W3[tid]; }
    if (tid == 0) sb3[0] = b3[0];
    __syncthreads();

    const float2* W1r = (const float2*)sW1;
    const float*  B1  = sb1;
    const float4* W2r = (const float4*)sW2;
    const float*  B2  = sb2;
    const float*  W3r = sW3;
    const float   b3v = sb3[0];

    const int gid = blockIdx.x * 256 + tid;
    const int npts_mask = (1 << lgnpts) - 1;
    const int st = gid >> lgnpts;
    const int k  = gid & npts_mask;

    const float t = ts[st];
    const float s = __builtin_amdgcn_exp2f(fmaf((float)k, dx, lo));

    float h, hacc;
    MLP_BODY(W1r, B1, W2r, B2, W3r, b3v, t, s, 1.0f, h, hacc)

    const float hp = h * (1.0f - h) * hacc;   // dh/ds
    T[gid] = make_float2(h, hp);
}

// ---------------------------------------------------------------------------
// Kernel 2: SDE path integration using the table.
// ---------------------------------------------------------------------------
__global__ __launch_bounds__(256) void path_kernel(
    const float* __restrict__ noise,   // (NSTEPS, BATCH)
    const float* __restrict__ ts,      // (NSTEPS+1)
    const float* __restrict__ wq,      // scalar
    const float2* __restrict__ T,      // (NSTEPS, npts)
    int lgnpts, float lo, float invdx,
    float* __restrict__ out)           // (BATCH)
{
    __shared__ float2 sdt[NSTEPS];
    const int tid = threadIdx.x;
    if (tid < NSTEPS) {
        const float dtv = ts[tid + 1] - ts[tid];
        sdt[tid] = make_float2(dtv, __builtin_sqrtf(dtv));
    }
    __syncthreads();

    const int gid = blockIdx.x * 256 + tid;
    const float* np_ = noise + gid;
    const int npts = 1 << lgnpts;
    const float umax = (float)(npts - 1) - 0.001f;

    float s   = 1.0f;
    float pnl = 0.0f;

    #pragma unroll 1
    for (int st = 0; st < NSTEPS; ++st) {
        const float2 dts = sdt[st];
        const float dW = np_[(size_t)st * BATCH] * dts.y;

        // table lookup: h, h' at (t_st, s)
        const float x = __builtin_amdgcn_logf(s);              // log2(s), s>0 always
        const float u = fminf(fmaxf((x - lo) * invdx, 0.0f), umax);
        const int   i0 = (int)u;
        const float f  = u - (float)i0;
        const float2* Trow = T + ((size_t)st << lgnpts);
        const float2 e0 = Trow[i0];
        const float2 e1 = Trow[i0 + 1];
        const float h  = fmaf(f, e1.x - e0.x, e0.x);
        const float hp = fmaf(f, e1.y - e0.y, e0.y);

        // Milstein update (MU = SIGMA = 1):
        const float mil  = 0.5f * fmaf(dW, dW, -dts.x);
        const float sum1 = dts.x + dW;
        const float g1   = s * h;
        const float dg1  = fmaf(s * s, hp, g1);
        pnl = fmaf(dg1, mil, fmaf(g1, sum1, pnl));
        s   = fmaf(s, sum1 + mil, s);
    }

    const float z = fmaxf(0.0f, s - 3.0f);
    const float d = z - pnl - wq[0];
    out[gid] = d * d;
}

// ---------------------------------------------------------------------------
// Fallback: direct per-thread MLP evaluation (R4 kernel) if ws too small.
// ---------------------------------------------------------------------------
__global__ __launch_bounds__(256, 3) void deep_hedging_direct(
    const float* __restrict__ noise, const float* __restrict__ ts,
    const float* __restrict__ w,
    const float* __restrict__ W1, const float* __restrict__ b1,
    const float* __restrict__ W2, const float* __restrict__ b2,
    const float* __restrict__ W3, const float* __restrict__ b3,
    float* __restrict__ out)
{
    __shared__ __align__(16) float sW1[64];
    __shared__ float sb1[32];
    __shared__ __align__(16) float sW2[1024];
    __shared__ float sb2[32];
    __shared__ float sW3[32];
    __shared__ float sb3w[2];
    __shared__ float sts[NSTEPS + 1];

    const int tid = threadIdx.x;
    for (int i = tid; i < 1024; i += 256) sW2[i] = W2[i];
    if (tid < 64) sW1[tid] = W1[tid];
    if (tid < 32) { sb1[tid] = b1[tid]; sb2[tid] = b2[tid]; sW3[tid] = W3[tid]; }
    if (tid == 0) { sb3w[0] = b3[0]; sb3w[1] = w[0]; }
    for (int i = tid; i < NSTEPS + 1; i += 256) sts[i] = ts[i];
    __syncthreads();

    const int gid = blockIdx.x * 256 + tid;
    const float* np_ = noise + gid;

    float s   = 1.0f;
    float pnl = 0.0f;
    const float b3v = sb3w[0];
    const float wv_ = sb3w[1];

    #pragma unroll 1
    for (int st = 0; st < NSTEPS; ++st) {
        int zr = 0;
        asm volatile("" : "+v"(zr));   // block LICM of weight loads
        const float2* W1r = (const float2*)sW1 + zr;
        const float*  B1  = sb1 + zr;
        const float4* W2r = (const float4*)sW2 + zr;
        const float*  B2  = sb2 + zr;
        const float*  W3r = sW3 + zr;

        const float t  = sts[st];
        const float dt = sts[st + 1] - t;
        const float dW = np_[(size_t)st * BATCH] * __builtin_sqrtf(dt);
        const float sd = s;

        float h, hacc;
        MLP_BODY(W1r, B1, W2r, B2, W3r, b3v, t, s, sd, h, hacc)
        const float hd = h * (1.0f - h) * hacc;

        const float mil = 0.5f * (dW * dW - dt);
        const float g1  = s * h;
        const float dg1 = fmaf(sd, h, s * hd);
        const float snew = s + s * dt + s * dW + sd * mil;
        pnl = pnl + g1 * dt + g1 * dW + dg1 * mil;
        s = snew;
    }

    const float z = fmaxf(0.0f, s - 3.0f);
    const float d = z - pnl - wv_;
    out[gid] = d * d;
}

extern "C" void kernel_launch(void* const* d_in, const int* in_sizes, int n_in,
                              void* d_out, int out_size, void* d_ws, size_t ws_size,
                              hipStream_t stream) {
    const float* noise = (const float*)d_in[0];
    const float* ts    = (const float*)d_in[1];
    const float* w     = (const float*)d_in[2];
    const float* W1    = (const float*)d_in[3];
    const float* b1    = (const float*)d_in[4];
    const float* W2    = (const float*)d_in[5];
    const float* b2    = (const float*)d_in[6];
    const float* W3    = (const float*)d_in[7];
    const float* b3    = (const float*)d_in[8];
    float* out = (float*)d_out;

    // choose table size to fit workspace (deterministic: ws_size is fixed)
    int lgnpts = 11;                                   // 2048 points -> 4 MB
    while (lgnpts > 5 &&
           ((size_t)NSTEPS << lgnpts) * sizeof(float2) > ws_size)
        --lgnpts;

    if (lgnpts >= 9) {   // >=512 points: table path is accurate enough
        const int npts = 1 << lgnpts;
        const float dx = LOGSPAN / (float)npts;
        const float invdx = (float)npts / LOGSPAN;
        float2* T = (float2*)d_ws;

        dim3 tb(256), tg((NSTEPS * npts) / 256);
        table_kernel<<<tg, tb, 0, stream>>>(ts, W1, b1, W2, b2, W3, b3,
                                            T, lgnpts, LOGLO, dx);
        dim3 pb(256), pg(BATCH / 256);
        path_kernel<<<pg, pb, 0, stream>>>(noise, ts, w, T, lgnpts, LOGLO,
                                           invdx, out);
    } else {
        dim3 grid(BATCH / 256), block(256);
        deep_hedging_direct<<<grid, block, 0, stream>>>(noise, ts, w, W1, b1,
                                                        W2, b2, W3, b3, out);
    }
}

// Round 6
// 92.464 us; speedup vs baseline: 1018.8484x; 1.4698x over previous
//
#include <hip/hip_runtime.h>
#include <math.h>

#define BATCH 131072
#define NSTEPS 256
#define LOGLO -16.0f
#define LOGSPAN 26.0f

using f32x2 = __attribute__((ext_vector_type(2))) float;

__device__ __forceinline__ float fast_exp(float x) {
    return __builtin_amdgcn_exp2f(x * 1.44269504088896340736f);
}
__device__ __forceinline__ float fast_rcp(float x) {
    return __builtin_amdgcn_rcpf(x);
}
__device__ __forceinline__ float sigmoidf_fast(float x) {
    return fast_rcp(1.0f + fast_exp(-x));
}

#define REP32(M) M(0) M(1) M(2) M(3) M(4) M(5) M(6) M(7) \
                 M(8) M(9) M(10) M(11) M(12) M(13) M(14) M(15) \
                 M(16) M(17) M(18) M(19) M(20) M(21) M(22) M(23) \
                 M(24) M(25) M(26) M(27) M(28) M(29) M(30) M(31)

#define REP8(M) M(0) M(1) M(2) M(3) M(4) M(5) M(6) M(7)

// Shared MLP+tangent body (see R4). Produces h and pre-sigmoid tangent acc.
#define MLP_BODY(W1r, B1, W2r, B2, W3r, b3v, t, s, sd, H, HACC) \
    { \
        const float __t = (t), __s = (s), __sd = (sd); \
        f32x2 acc2 = {(b3v), 0.0f}; \
        REP32(MLP_L1) \
        REP32(MLP_ROW) \
        H = sigmoidf_fast(acc2.x); \
        HACC = acc2.y; \
    }

#define MLP_L1(j) f32x2 at##j; { \
    const float2 wv = W1r[j]; \
    const float z  = fmaf(wv.x, __t, fmaf(wv.y, __s, B1[j])); \
    const float zd = wv.y * __sd; \
    const float sg = sigmoidf_fast(z); \
    const float da = sg * (1.0f + z * (1.0f - sg)); \
    at##j = (f32x2){z * sg, da * zd}; }

#define MLP_ROW(j) { \
    const float4 q0 = W2r[(j) * 8 + 0]; \
    const float4 q1 = W2r[(j) * 8 + 1]; \
    const float4 q2 = W2r[(j) * 8 + 2]; \
    const float4 q3 = W2r[(j) * 8 + 3]; \
    const float4 q4 = W2r[(j) * 8 + 4]; \
    const float4 q5 = W2r[(j) * 8 + 5]; \
    const float4 q6 = W2r[(j) * 8 + 6]; \
    const float4 q7 = W2r[(j) * 8 + 7]; \
    f32x2 zza = {B2[j], 0.0f}; \
    f32x2 zzb = {0.0f, 0.0f}; \
    zza += (f32x2){q0.x, q0.x} * at0;  zzb += (f32x2){q0.y, q0.y} * at1; \
    zza += (f32x2){q0.z, q0.z} * at2;  zzb += (f32x2){q0.w, q0.w} * at3; \
    zza += (f32x2){q1.x, q1.x} * at4;  zzb += (f32x2){q1.y, q1.y} * at5; \
    zza += (f32x2){q1.z, q1.z} * at6;  zzb += (f32x2){q1.w, q1.w} * at7; \
    zza += (f32x2){q2.x, q2.x} * at8;  zzb += (f32x2){q2.y, q2.y} * at9; \
    zza += (f32x2){q2.z, q2.z} * at10; zzb += (f32x2){q2.w, q2.w} * at11; \
    zza += (f32x2){q3.x, q3.x} * at12; zzb += (f32x2){q3.y, q3.y} * at13; \
    zza += (f32x2){q3.z, q3.z} * at14; zzb += (f32x2){q3.w, q3.w} * at15; \
    zza += (f32x2){q4.x, q4.x} * at16; zzb += (f32x2){q4.y, q4.y} * at17; \
    zza += (f32x2){q4.z, q4.z} * at18; zzb += (f32x2){q4.w, q4.w} * at19; \
    zza += (f32x2){q5.x, q5.x} * at20; zzb += (f32x2){q5.y, q5.y} * at21; \
    zza += (f32x2){q5.z, q5.z} * at22; zzb += (f32x2){q5.w, q5.w} * at23; \
    zza += (f32x2){q6.x, q6.x} * at24; zzb += (f32x2){q6.y, q6.y} * at25; \
    zza += (f32x2){q6.z, q6.z} * at26; zzb += (f32x2){q6.w, q6.w} * at27; \
    zza += (f32x2){q7.x, q7.x} * at28; zzb += (f32x2){q7.y, q7.y} * at29; \
    zza += (f32x2){q7.z, q7.z} * at30; zzb += (f32x2){q7.w, q7.w} * at31; \
    const f32x2 zzt = zza + zzb; \
    const float zv  = zzt.x; \
    const float sg  = sigmoidf_fast(zv); \
    const float da  = sg * (1.0f + zv * (1.0f - sg)); \
    const float w3  = W3r[j]; \
    acc2 += (f32x2){w3, w3} * (f32x2){zv * sg, da * zzt.y}; \
}

// ---------------------------------------------------------------------------
// Kernel 1: per-step lookup table T[st][k] = {h, dh/ds} at s = 2^(lo+k*dx).
// ---------------------------------------------------------------------------
__global__ __launch_bounds__(256) void table_kernel(
    const float* __restrict__ ts,
    const float* __restrict__ W1, const float* __restrict__ b1,
    const float* __restrict__ W2, const float* __restrict__ b2,
    const float* __restrict__ W3, const float* __restrict__ b3,
    float2* __restrict__ T, int lgnpts, float lo, float dx)
{
    __shared__ __align__(16) float sW1[64];
    __shared__ float sb1[32];
    __shared__ __align__(16) float sW2[1024];
    __shared__ float sb2[32];
    __shared__ float sW3[32];
    __shared__ float sb3[1];

    const int tid = threadIdx.x;
    for (int i = tid; i < 1024; i += 256) sW2[i] = W2[i];
    if (tid < 64) sW1[tid] = W1[tid];
    if (tid < 32) { sb1[tid] = b1[tid]; sb2[tid] = b2[tid]; sW3[tid] = W3[tid]; }
    if (tid == 0) sb3[0] = b3[0];
    __syncthreads();

    const float2* W1r = (const float2*)sW1;
    const float*  B1  = sb1;
    const float4* W2r = (const float4*)sW2;
    const float*  B2  = sb2;
    const float*  W3r = sW3;
    const float   b3v = sb3[0];

    const int gid = blockIdx.x * 256 + tid;
    const int npts_mask = (1 << lgnpts) - 1;
    const int st = gid >> lgnpts;
    const int k  = gid & npts_mask;

    const float t = ts[st];
    const float s = __builtin_amdgcn_exp2f(fmaf((float)k, dx, lo));

    float h, hacc;
    MLP_BODY(W1r, B1, W2r, B2, W3r, b3v, t, s, 1.0f, h, hacc)

    const float hp = h * (1.0f - h) * hacc;   // dh/ds
    T[gid] = make_float2(h, hp);
}

// ---------------------------------------------------------------------------
// Kernel 2: SDE path integration. s-recurrence is table-independent, so we
// run it ahead in chunks of 8 and issue all table gathers before consuming
// them -> 16+ loads in flight per wave (latency hidden by ILP, since TLP is
// capped at 8 waves/CU by grid size).
// ---------------------------------------------------------------------------
__global__ __launch_bounds__(256, 2) void path_kernel(
    const float* __restrict__ noise,   // (NSTEPS, BATCH)
    const float* __restrict__ ts,      // (NSTEPS+1)
    const float* __restrict__ wq,      // scalar
    const float2* __restrict__ T,      // (NSTEPS, npts)
    int lgnpts, float lo, float invdx,
    float* __restrict__ out)           // (BATCH)
{
    __shared__ float2 sdt[NSTEPS];
    const int tid = threadIdx.x;
    if (tid < NSTEPS) {
        const float dtv = ts[tid + 1] - ts[tid];
        sdt[tid] = make_float2(dtv, __builtin_sqrtf(dtv));
    }
    __syncthreads();

    const int gid = blockIdx.x * 256 + tid;
    const float* np_ = noise + gid;
    const int npts = 1 << lgnpts;
    const float umax = (float)(npts - 1) - 0.001f;

    float s   = 1.0f;
    float pnl = 0.0f;

    // preload chunk 0 noise
    #define NLD0(k) float n##k = np_[(size_t)(k) * BATCH];
    REP8(NLD0)
    #undef NLD0

    #pragma unroll 1
    for (int c = 0; c < NSTEPS / 8; ++c) {
        const int base = c * 8;

        // prefetch next chunk's noise (independent loads, issued early)
        const float* nb = np_ + ((size_t)base + 8) * BATCH;
        const bool more = (c < NSTEPS / 8 - 1);
        #define NPF(k) const float m##k = more ? nb[(size_t)(k) * BATCH] : 0.0f;
        REP8(NPF)
        #undef NPF

        // s-chain (cheap, serial) + issue all 16 table gathers
        #define CH(k) \
            const float2 dts##k = sdt[base + k]; \
            const float dW##k   = n##k * dts##k.y; \
            const float mil##k  = 0.5f * fmaf(dW##k, dW##k, -dts##k.x); \
            const float sum1##k = dts##k.x + dW##k; \
            const float sv##k   = s; \
            s = fmaf(s, sum1##k + mil##k, s); \
            const float x##k = __builtin_amdgcn_logf(sv##k); \
            const float u##k = fminf(fmaxf((x##k - lo) * invdx, 0.0f), umax); \
            const int   i0##k = (int)u##k; \
            const float f##k  = u##k - (float)i0##k; \
            const float2* Tr##k = T + ((size_t)(base + k) << lgnpts); \
            const float2 e0##k = Tr##k[i0##k]; \
            const float2 e1##k = Tr##k[i0##k + 1];
        REP8(CH)
        #undef CH

        // consume gathers into pnl
        #define PN(k) { \
            const float h  = fmaf(f##k, e1##k.x - e0##k.x, e0##k.x); \
            const float hp = fmaf(f##k, e1##k.y - e0##k.y, e0##k.y); \
            const float g1  = sv##k * h; \
            const float dg1 = fmaf(sv##k * sv##k, hp, g1); \
            pnl = fmaf(dg1, mil##k, fmaf(g1, sum1##k, pnl)); }
        REP8(PN)
        #undef PN

        // rotate prefetched noise into place
        #define NRT(k) n##k = m##k;
        REP8(NRT)
        #undef NRT
    }

    const float z = fmaxf(0.0f, s - 3.0f);
    const float d = z - pnl - wq[0];
    out[gid] = d * d;
}

// ---------------------------------------------------------------------------
// Fallback: direct per-thread MLP evaluation (R4 kernel) if ws too small.
// ---------------------------------------------------------------------------
__global__ __launch_bounds__(256, 3) void deep_hedging_direct(
    const float* __restrict__ noise, const float* __restrict__ ts,
    const float* __restrict__ w,
    const float* __restrict__ W1, const float* __restrict__ b1,
    const float* __restrict__ W2, const float* __restrict__ b2,
    const float* __restrict__ W3, const float* __restrict__ b3,
    float* __restrict__ out)
{
    __shared__ __align__(16) float sW1[64];
    __shared__ float sb1[32];
    __shared__ __align__(16) float sW2[1024];
    __shared__ float sb2[32];
    __shared__ float sW3[32];
    __shared__ float sb3w[2];
    __shared__ float sts[NSTEPS + 1];

    const int tid = threadIdx.x;
    for (int i = tid; i < 1024; i += 256) sW2[i] = W2[i];
    if (tid < 64) sW1[tid] = W1[tid];
    if (tid < 32) { sb1[tid] = b1[tid]; sb2[tid] = b2[tid]; sW3[tid] = W3[tid]; }
    if (tid == 0) { sb3w[0] = b3[0]; sb3w[1] = w[0]; }
    for (int i = tid; i < NSTEPS + 1; i += 256) sts[i] = ts[i];
    __syncthreads();

    const int gid = blockIdx.x * 256 + tid;
    const float* np_ = noise + gid;

    float s   = 1.0f;
    float pnl = 0.0f;
    const float b3v = sb3w[0];
    const float wv_ = sb3w[1];

    #pragma unroll 1
    for (int st = 0; st < NSTEPS; ++st) {
        int zr = 0;
        asm volatile("" : "+v"(zr));   // block LICM of weight loads
        const float2* W1r = (const float2*)sW1 + zr;
        const float*  B1  = sb1 + zr;
        const float4* W2r = (const float4*)sW2 + zr;
        const float*  B2  = sb2 + zr;
        const float*  W3r = sW3 + zr;

        const float t  = sts[st];
        const float dt = sts[st + 1] - t;
        const float dW = np_[(size_t)st * BATCH] * __builtin_sqrtf(dt);
        const float sd = s;

        float h, hacc;
        MLP_BODY(W1r, B1, W2r, B2, W3r, b3v, t, s, sd, h, hacc)
        const float hd = h * (1.0f - h) * hacc;

        const float mil = 0.5f * (dW * dW - dt);
        const float g1  = s * h;
        const float dg1 = fmaf(sd, h, s * hd);
        const float snew = s + s * dt + s * dW + sd * mil;
        pnl = pnl + g1 * dt + g1 * dW + dg1 * mil;
        s = snew;
    }

    const float z = fmaxf(0.0f, s - 3.0f);
    const float d = z - pnl - wv_;
    out[gid] = d * d;
}

extern "C" void kernel_launch(void* const* d_in, const int* in_sizes, int n_in,
                              void* d_out, int out_size, void* d_ws, size_t ws_size,
                              hipStream_t stream) {
    const float* noise = (const float*)d_in[0];
    const float* ts    = (const float*)d_in[1];
    const float* w     = (const float*)d_in[2];
    const float* W1    = (const float*)d_in[3];
    const float* b1    = (const float*)d_in[4];
    const float* W2    = (const float*)d_in[5];
    const float* b2    = (const float*)d_in[6];
    const float* W3    = (const float*)d_in[7];
    const float* b3    = (const float*)d_in[8];
    float* out = (float*)d_out;

    // choose table size to fit workspace (deterministic: ws_size is fixed)
    int lgnpts = 11;                                   // 2048 points -> 4 MB
    while (lgnpts > 5 &&
           ((size_t)NSTEPS << lgnpts) * sizeof(float2) > ws_size)
        --lgnpts;

    if (lgnpts >= 9) {   // >=512 points: table path is accurate enough
        const int npts = 1 << lgnpts;
        const float dx = LOGSPAN / (float)npts;
        const float invdx = (float)npts / LOGSPAN;
        float2* T = (float2*)d_ws;

        dim3 tb(256), tg((NSTEPS * npts) / 256);
        table_kernel<<<tg, tb, 0, stream>>>(ts, W1, b1, W2, b2, W3, b3,
                                            T, lgnpts, LOGLO, dx);
        dim3 pb(256), pg(BATCH / 256);
        path_kernel<<<pg, pb, 0, stream>>>(noise, ts, w, T, lgnpts, LOGLO,
                                           invdx, out);
    } else {
        dim3 grid(BATCH / 256), block(256);
        deep_hedging_direct<<<grid, block, 0, stream>>>(noise, ts, w, W1, b1,
                                                        W2, b2, W3, b3, out);
    }
}